// Round 1
// baseline (813.362 us; speedup 1.0000x reference)
//
#include <hip/hip_runtime.h>
#include <hip/hip_bf16.h>

typedef __attribute__((ext_vector_type(8))) short short8;
typedef __attribute__((ext_vector_type(4))) float f32x4;

// Problem constants: B=8, S=1024, D=1024, H=16, hd=64

__device__ __forceinline__ void gload16(const void* g, void* l) {
  __builtin_amdgcn_global_load_lds((const __attribute__((address_space(1))) void*)g,
                                   (__attribute__((address_space(3))) void*)l, 16, 0, 0);
}

__device__ __forceinline__ short f2bf(float x) {
  __hip_bfloat16 h = __float2bfloat16(x);
  return __builtin_bit_cast(short, h);
}

// ---------------- X fp32 -> bf16 ----------------
__global__ void k_conv_x(const float* __restrict__ X, __hip_bfloat16* __restrict__ Xb) {
  int i = (blockIdx.x * 256 + threadIdx.x) * 4;
  float4 v = *(const float4*)(X + i);
  __hip_bfloat16 t[4];
  t[0] = __float2bfloat16(v.x); t[1] = __float2bfloat16(v.y);
  t[2] = __float2bfloat16(v.z); t[3] = __float2bfloat16(v.w);
  *(uint2*)(Xb + i) = *(uint2*)t;
}

// ---------------- W fp32 [k][n] -> Wt bf16 [n][k], q/k/v concat ----------------
__global__ void k_transpose_w(const float* __restrict__ Wq, const float* __restrict__ Wk,
                              const float* __restrict__ Wv, __hip_bfloat16* __restrict__ Wt) {
  __shared__ float t[32][33];
  const int w = blockIdx.z;
  const float* W = (w == 0) ? Wq : ((w == 1) ? Wk : Wv);
  const int k0 = blockIdx.x * 32, n0 = blockIdx.y * 32;
  const int tx = threadIdx.x, ty = threadIdx.y;  // (32,8)
  #pragma unroll
  for (int i = 0; i < 4; ++i)
    t[ty + i * 8][tx] = W[(size_t)(k0 + ty + i * 8) * 1024 + n0 + tx];
  __syncthreads();
  __hip_bfloat16* o = Wt + (size_t)w * 1024 * 1024;
  #pragma unroll
  for (int i = 0; i < 4; ++i)
    o[(size_t)(n0 + ty + i * 8) * 1024 + k0 + tx] = __float2bfloat16(t[tx][ty + i * 8]);
}

// ---------------- QKV projection: C[8192][3072] = Xb[8192][1024] * Wt^T ----------------
// m97-style: 128x128 tile, BK=64, 4 waves (2x2 of 64x64), global_load_lds width 16.
__global__ __launch_bounds__(256) void k_qkv_gemm(
    const __hip_bfloat16* __restrict__ Xb,   // [8192][1024]
    const __hip_bfloat16* __restrict__ Wt,   // [3072][1024]
    const float* __restrict__ bq, const float* __restrict__ bk, const float* __restrict__ bv,
    __hip_bfloat16* __restrict__ Out)        // [3][8192][1024]
{
  __shared__ __hip_bfloat16 lA[128 * 64];
  __shared__ __hip_bfloat16 lB[128 * 64];
  const int tid = threadIdx.x;
  const int wv = tid >> 6, lane = tid & 63;
  const int m0 = blockIdx.x * 128;
  const int n0 = blockIdx.y * 128;
  const int wm = wv >> 1, wn = wv & 1;

  f32x4 acc[4][4];
  #pragma unroll
  for (int i = 0; i < 4; ++i)
    #pragma unroll
    for (int j = 0; j < 4; ++j) acc[i][j] = (f32x4)0.0f;

  const int srow = lane >> 3;        // 0..7 rows per 1KB chunk
  const int scol = (lane & 7) * 8;   // element col within 64-wide row

  for (int kt = 0; kt < 16; ++kt) {
    const __hip_bfloat16* gA = Xb + (size_t)m0 * 1024 + kt * 64;
    const __hip_bfloat16* gB = Wt + (size_t)n0 * 1024 + kt * 64;
    #pragma unroll
    for (int i = 0; i < 4; ++i) {
      int r0 = wv * 32 + i * 8;
      gload16(gA + (size_t)(r0 + srow) * 1024 + scol, &lA[r0 * 64]);
      gload16(gB + (size_t)(r0 + srow) * 1024 + scol, &lB[r0 * 64]);
    }
    __syncthreads();
    #pragma unroll
    for (int ks = 0; ks < 2; ++ks) {
      short8 af[4], bfr[4];
      #pragma unroll
      for (int mi = 0; mi < 4; ++mi)
        af[mi] = *(const short8*)&lA[(wm * 64 + mi * 16 + (lane & 15)) * 64 + ks * 32 + (lane >> 4) * 8];
      #pragma unroll
      for (int ni = 0; ni < 4; ++ni)
        bfr[ni] = *(const short8*)&lB[(wn * 64 + ni * 16 + (lane & 15)) * 64 + ks * 32 + (lane >> 4) * 8];
      #pragma unroll
      for (int mi = 0; mi < 4; ++mi)
        #pragma unroll
        for (int ni = 0; ni < 4; ++ni)
          acc[mi][ni] = __builtin_amdgcn_mfma_f32_16x16x32_bf16(af[mi], bfr[ni], acc[mi][ni], 0, 0, 0);
    }
    __syncthreads();
  }

  const int which = n0 >> 10;
  const float* bias = (which == 0) ? bq : ((which == 1) ? bk : bv);
  __hip_bfloat16* O = Out + (size_t)which * (8192ull * 1024);
  #pragma unroll
  for (int ni = 0; ni < 4; ++ni) {
    int col = (n0 & 1023) + wn * 64 + ni * 16 + (lane & 15);
    float bb = bias[col];
    #pragma unroll
    for (int mi = 0; mi < 4; ++mi) {
      int rowb = m0 + wm * 64 + mi * 16 + (lane >> 4) * 4;
      #pragma unroll
      for (int r = 0; r < 4; ++r)
        O[(size_t)(rowb + r) * 1024 + col] = __float2bfloat16(acc[mi][ni][r] + bb);
    }
  }
}

// ---------------- V [B,S,D] bf16 -> Vt [B*H][64][1024] bf16 ----------------
__global__ void k_transpose_v(const __hip_bfloat16* __restrict__ V, __hip_bfloat16* __restrict__ Vt) {
  __shared__ __hip_bfloat16 t[32][33];
  const int bh = blockIdx.z, b = bh >> 4, h = bh & 15;
  const int s0 = blockIdx.x * 32, d0 = blockIdx.y * 32;
  const int tx = threadIdx.x, ty = threadIdx.y;  // (32,8)
  const __hip_bfloat16* Vb = V + ((size_t)b * 1024) * 1024 + h * 64;
  #pragma unroll
  for (int i = 0; i < 4; ++i)
    t[ty + i * 8][tx] = Vb[(size_t)(s0 + ty + i * 8) * 1024 + d0 + tx];
  __syncthreads();
  __hip_bfloat16* o = Vt + ((size_t)bh * 64 + d0) * 1024 + s0;
  #pragma unroll
  for (int i = 0; i < 4; ++i)
    o[(size_t)(ty + i * 8) * 1024 + tx] = t[tx][ty + i * 8];
}

// ---------------- Attention: per (b,h, 64-row q-tile), two-pass online softmax ----------------
// LDS tiles are XOR-swizzled (chunk ^= row&7 at 16B granularity) to kill the
// 16-way bank conflicts of row-stride 128B/256B fragment reads. Staging keeps
// a LINEAR LDS destination (global_load_lds requirement) and pre-swizzles the
// per-lane GLOBAL source address instead (rule #21 / HK pattern).
__global__ __launch_bounds__(256) void k_attn(
    const __hip_bfloat16* __restrict__ Qb,  // [8][1024][1024]
    const __hip_bfloat16* __restrict__ Kb,  // [8][1024][1024]
    const __hip_bfloat16* __restrict__ Vt,  // [128][64][1024]
    float* __restrict__ attn,               // [8][1024][1024]
    float* __restrict__ aw)                 // [128][1024][1024]
{
  __shared__ __hip_bfloat16 lK[128 * 64];   // K tile [128][64] (swz); reused as Vt tile [64][128] (swz)
  __shared__ float lS[64 * 128];            // P tile fp32 [64 q][128 k] (swz)
  const int tid = threadIdx.x;
  const int wv = tid >> 6, lane = tid & 63;
  const int ln15 = lane & 15, lnhi = lane >> 4;
  const int bh = blockIdx.y, b = bh >> 4, h = bh & 15;
  const int q0 = blockIdx.x * 64;
  const size_t head_off = ((size_t)b * 1024) * 1024 + h * 64;
  const float C = 0.18033688f;  // (1/sqrt(64)) * log2(e): softmax in exp2 domain

  // Q fragments held in registers for the whole kernel (wave wv owns q rows q0+wv*16 .. +15)
  short8 qf[2];
  {
    const __hip_bfloat16* qrow =
        Qb + head_off + (size_t)(q0 + wv * 16 + ln15) * 1024 + lnhi * 8;
    qf[0] = *(const short8*)qrow;
    qf[1] = *(const short8*)(qrow + 32);
  }

  float m2[4], l_run[4];
  #pragma unroll
  for (int r = 0; r < 4; ++r) { m2[r] = -3.0e38f; l_run[r] = 0.0f; }

  const int ksrow = lane >> 3, kchk = lane & 7;  // K-stage: 8 rows x 8 chunks per wave-instr

  // ---- pass 1: running row max + sumexp (log2 domain) ----
  for (int kt = 0; kt < 8; ++kt) {
    const __hip_bfloat16* gK = Kb + head_off + (size_t)(kt * 128) * 1024;
    #pragma unroll
    for (int i = 0; i < 4; ++i) {
      int r0 = wv * 32 + i * 8;
      int row = r0 + ksrow;
      gload16(gK + (size_t)row * 1024 + ((kchk ^ (row & 7)) << 3), &lK[r0 * 64]);
    }
    __syncthreads();
    f32x4 s[8];
    #pragma unroll
    for (int ni = 0; ni < 8; ++ni) s[ni] = (f32x4)0.0f;
    __builtin_amdgcn_s_setprio(1);
    #pragma unroll
    for (int ks = 0; ks < 2; ++ks) {
      #pragma unroll
      for (int ni = 0; ni < 8; ++ni) {
        int R = ni * 16 + ln15;
        short8 kf = *(const short8*)&lK[R * 64 + (((ks * 4 + lnhi) ^ (R & 7)) << 3)];
        s[ni] = __builtin_amdgcn_mfma_f32_16x16x32_bf16(qf[ks], kf, s[ni], 0, 0, 0);
      }
    }
    __builtin_amdgcn_s_setprio(0);
    __syncthreads();  // all waves done reading lK before next stage
    #pragma unroll
    for (int r = 0; r < 4; ++r) {
      float mt = -3.0e38f;
      #pragma unroll
      for (int ni = 0; ni < 8; ++ni) mt = fmaxf(mt, s[ni][r]);
      float mt2 = mt * C;
      #pragma unroll
      for (int off = 1; off < 16; off <<= 1) mt2 = fmaxf(mt2, __shfl_xor(mt2, off, 64));
      float mnew = fmaxf(m2[r], mt2);
      float sum = 0.0f;
      #pragma unroll
      for (int ni = 0; ni < 8; ++ni) sum += exp2f(fmaf(s[ni][r], C, -mnew));
      #pragma unroll
      for (int off = 1; off < 16; off <<= 1) sum += __shfl_xor(sum, off, 64);
      l_run[r] = l_run[r] * exp2f(m2[r] - mnew) + sum;
      m2[r] = mnew;
    }
  }

  // p = exp2(s*C - m2)/l = exp2(s*C - (m2 + log2 l)) : fold 1/l into the constant
  float c2[4];
  #pragma unroll
  for (int r = 0; r < 4; ++r) c2[r] = m2[r] + __log2f(l_run[r]);

  f32x4 o[4];
  #pragma unroll
  for (int ni = 0; ni < 4; ++ni) o[ni] = (f32x4)0.0f;

  const int rl = wv * 16 + lnhi * 4;

  // ---- pass 2: recompute S, stage normalized P in LDS, coalesced aw store, O = P*V ----
  for (int kt = 0; kt < 8; ++kt) {
    const __hip_bfloat16* gK = Kb + head_off + (size_t)(kt * 128) * 1024;
    #pragma unroll
    for (int i = 0; i < 4; ++i) {
      int r0 = wv * 32 + i * 8;
      int row = r0 + ksrow;
      gload16(gK + (size_t)row * 1024 + ((kchk ^ (row & 7)) << 3), &lK[r0 * 64]);
    }
    __syncthreads();
    f32x4 s[8];
    #pragma unroll
    for (int ni = 0; ni < 8; ++ni) s[ni] = (f32x4)0.0f;
    __builtin_amdgcn_s_setprio(1);
    #pragma unroll
    for (int ks = 0; ks < 2; ++ks) {
      #pragma unroll
      for (int ni = 0; ni < 8; ++ni) {
        int R = ni * 16 + ln15;
        short8 kf = *(const short8*)&lK[R * 64 + (((ks * 4 + lnhi) ^ (R & 7)) << 3)];
        s[ni] = __builtin_amdgcn_mfma_f32_16x16x32_bf16(qf[ks], kf, s[ni], 0, 0, 0);
      }
    }
    __builtin_amdgcn_s_setprio(0);
    // write normalized p into swizzled fp32 LDS tile (conflict-free: 16-lane
    // groups write same-row consecutive cols; groups differ in row -> XOR splits banks)
    #pragma unroll
    for (int ni = 0; ni < 8; ++ni) {
      int c = ni * 16 + ln15;
      #pragma unroll
      for (int r = 0; r < 4; ++r) {
        int row = rl + r;
        float p = exp2f(fmaf(s[ni][r], C, -c2[r]));
        *(float*)((char*)lS + (((row << 9) + (c << 2)) ^ ((row & 7) << 4))) = p;
      }
    }
    __syncthreads();  // lK reads (S recompute) done; lS fully written
    // stage Vt tile [64 hd][128 keys] into lK region (async), then coalesced aw
    // store from lS overlapping the V load latency
    const __hip_bfloat16* gV = Vt + (size_t)bh * (64ull * 1024) + kt * 128;
    #pragma unroll
    for (int i = 0; i < 4; ++i) {
      int r0 = wv * 16 + i * 4;
      int row = r0 + lnhi;
      gload16(gV + (size_t)row * 1024 + ((ln15 ^ (row & 7)) << 3), &lK[r0 * 128]);
    }
    float* awb = aw + (size_t)bh * (1024ull * 1024) + (size_t)q0 * 1024 + kt * 128;
    #pragma unroll
    for (int i = 0; i < 8; ++i) {
      int idx = i * 256 + tid;
      int row = idx >> 5, ch = idx & 31;
      f32x4 v = *(const f32x4*)((const char*)lS + ((row << 9) + ((ch ^ (row & 7)) << 4)));
      *(f32x4*)(awb + (size_t)row * 1024 + ch * 4) = v;
    }
    __syncthreads();
    // O[16 x 64] += P[16 x 128] * V[128 x 64]; P fragments read from lS + cvt
    __builtin_amdgcn_s_setprio(1);
    #pragma unroll
    for (int ks = 0; ks < 4; ++ks) {
      int R = wv * 16 + ln15;
      int c0 = ks * 8 + lnhi * 2;  // 16B chunk index (32 per row)
      const char* bp = (const char*)lS + (R << 9);
      f32x4 pa = *(const f32x4*)(bp + ((c0 ^ (R & 7)) << 4));
      f32x4 pb = *(const f32x4*)(bp + (((c0 + 1) ^ (R & 7)) << 4));
      short8 pf;
      pf[0] = f2bf(pa[0]); pf[1] = f2bf(pa[1]); pf[2] = f2bf(pa[2]); pf[3] = f2bf(pa[3]);
      pf[4] = f2bf(pb[0]); pf[5] = f2bf(pb[1]); pf[6] = f2bf(pb[2]); pf[7] = f2bf(pb[3]);
      #pragma unroll
      for (int ni = 0; ni < 4; ++ni) {
        int Rv = ni * 16 + ln15;
        short8 vf = *(const short8*)&lK[Rv * 128 + (((ks * 4 + lnhi) ^ (Rv & 7)) << 3)];
        o[ni] = __builtin_amdgcn_mfma_f32_16x16x32_bf16(pf, vf, o[ni], 0, 0, 0);
      }
    }
    __builtin_amdgcn_s_setprio(0);
    __syncthreads();  // before next kt overwrites lK/lS
  }

  // epilogue: attn[b][q][h*64+d']
  #pragma unroll
  for (int ni = 0; ni < 4; ++ni) {
    int c = h * 64 + ni * 16 + ln15;
    #pragma unroll
    for (int r = 0; r < 4; ++r)
      attn[((size_t)b * 1024 + q0 + rl + r) * 1024 + c] = o[ni][r];
  }
}

extern "C" void kernel_launch(void* const* d_in, const int* in_sizes, int n_in,
                              void* d_out, int out_size, void* d_ws, size_t ws_size,
                              hipStream_t stream) {
  const float* x  = (const float*)d_in[0];
  const float* Wq = (const float*)d_in[1];
  const float* bq = (const float*)d_in[2];
  const float* Wk = (const float*)d_in[3];
  const float* bk = (const float*)d_in[4];
  const float* Wv = (const float*)d_in[5];
  const float* bv = (const float*)d_in[6];
  float* attn = (float*)d_out;                         // [8][1024][1024]
  float* aw   = (float*)d_out + 8ull * 1024 * 1024;    // [128][1024][1024]

  char* ws = (char*)d_ws;
  __hip_bfloat16* Xb  = (__hip_bfloat16*)(ws);                    // 16 MB
  __hip_bfloat16* Wt  = (__hip_bfloat16*)(ws + (16ull << 20));    // 6 MB
  __hip_bfloat16* QKV = (__hip_bfloat16*)(ws + (22ull << 20));    // 48 MB
  __hip_bfloat16* Vt  = (__hip_bfloat16*)(ws + (70ull << 20));    // 16 MB
  __hip_bfloat16* Qb = QKV;
  __hip_bfloat16* Kb = QKV + 8ull * 1024 * 1024;
  __hip_bfloat16* Vb = QKV + 16ull * 1024 * 1024;

  k_conv_x<<<8192, 256, 0, stream>>>(x, Xb);
  k_transpose_w<<<dim3(32, 32, 3), dim3(32, 8), 0, stream>>>(Wq, Wk, Wv, Wt);
  k_qkv_gemm<<<dim3(64, 24), 256, 0, stream>>>(Xb, Wt, bq, bk, bv, QKV);
  k_transpose_v<<<dim3(32, 2, 128), dim3(32, 8), 0, stream>>>(Vb, Vt);
  k_attn<<<dim3(16, 128), 256, 0, stream>>>(Qb, Kb, Vt, attn, aw);
}